// Round 19
// baseline (4372.398 us; speedup 1.0000x reference)
//
#include <hip/hip_runtime.h>
#include <math.h>

#define SEQ 256
#define BATCH 64
#define HID 1024
#define VOCAB 4000
#define H3 (3 * HID)
#define HSLICE (BATCH * HID)

typedef __attribute__((ext_vector_type(8))) short short8;
typedef __attribute__((ext_vector_type(4))) float f32x4;

__device__ inline unsigned short f2bf(float x) {
    unsigned int u = __builtin_bit_cast(unsigned int, x);
    unsigned int r = (u + 0x7fffu + ((u >> 16) & 1u)) >> 16;   // RNE
    return (unsigned short)r;
}
__device__ inline float bf2f(unsigned short h) {
    unsigned int u = ((unsigned int)h) << 16;
    return __builtin_bit_cast(float, u);
}

// ---------------------------------------------------------------------------
// Split f32 arrays into bf16 hi/lo pairs. h0 goes into slice 0 of the
// h-history (so the persistent kernel has no t==0 special case).
// ---------------------------------------------------------------------------
__global__ __launch_bounds__(256) void split_kernel(
    const float* __restrict__ W_hh, const float* __restrict__ W_out,
    const float* __restrict__ h0,
    unsigned short* __restrict__ whh_hi, unsigned short* __restrict__ whh_lo,
    unsigned short* __restrict__ wout_hi, unsigned short* __restrict__ wout_lo,
    unsigned short* __restrict__ h0_hi, unsigned short* __restrict__ h0_lo)
{
    const int NW = 3 * HID * HID;
    const int NO = VOCAB * HID;
    const int NH = BATCH * HID;
    const int total = NW + NO + NH;
    for (int i = blockIdx.x * blockDim.x + threadIdx.x; i < total;
         i += gridDim.x * blockDim.x) {
        const float* src; unsigned short *dh, *dl; int off;
        if (i < NW)           { src = W_hh;  dh = whh_hi;  dl = whh_lo;  off = i; }
        else if (i < NW + NO) { src = W_out; dh = wout_hi; dl = wout_lo; off = i - NW; }
        else                  { src = h0;    dh = h0_hi;   dl = h0_lo;   off = i - NW - NO; }
        float x = src[off];
        unsigned short hi = f2bf(x);
        dh[off] = hi;
        dl[off] = f2bf(x - bf2f(hi));
    }
}

// ---------------------------------------------------------------------------
// W_ih (3072 x 4000) -> W_ihT (4000 x 3072), 32x32 LDS tiles.
// ---------------------------------------------------------------------------
__global__ __launch_bounds__(256) void transpose_wih(
    const float* __restrict__ W_ih, float* __restrict__ W_ihT)
{
    __shared__ float tile[32][33];
    const int tx = threadIdx.x & 31;
    const int ty = threadIdx.x >> 5;          // 0..7
    const int r0 = blockIdx.y * 32;           // 3072-dim base
    const int c0 = blockIdx.x * 32;           // 4000-dim base
    #pragma unroll
    for (int k = 0; k < 4; ++k) {
        const int r = ty + k * 8;
        tile[r][tx] = W_ih[(size_t)(r0 + r) * VOCAB + c0 + tx];  // 4000%32==0
    }
    __syncthreads();
    #pragma unroll
    for (int k = 0; k < 4; ++k) {
        const int r = ty + k * 8;
        W_ihT[(size_t)(c0 + r) * H3 + r0 + tx] = tile[tx][r];
    }
}

__global__ void zero_barrier(int* b) {                    // 8192 ints (32 KB)
    b[blockIdx.x * 1024 + threadIdx.x] = 0;
}

// ---------------------------------------------------------------------------
// Persistent cooperative GRU + FUSED output GEMM.
// Recurrence structure = round-15/18 (best measured, 4.27 us/step): round-10
// LLC protocol (one flag/block, 4-flag polls, agent-scope write-through
// h-stores, no fences), parity-double-buffered red[], last-arriver publish.
// NEW: waves 4-7 compute the output-projection GEMM of slice t DURING step t
// (the 300 us standalone out_gemm disappears into recurrence poll-slack):
//   - visibility: at barrier#1 of step t, all 16 waves have collectively
//     polled all 16 producers of this mt-group for slice t -> slice t is
//     block-visible; any wave may read it.
//   - wave 4+nt (nt=0..3) computes C[(t-1)*64 + mt*16 .. +16][jt*64+nt*16
//     .. +16] over full K=1024: 32 chunks x {a_h*w_h, a_h*w_l, a_l*w_h}
//     — chunk-ascending, product order identical to the old out_gemm ->
//     bitwise-identical logits.
//   - tail after the t-loop: one extra poll (flags -> 256) + barrier, then
//     GEMM the final slice.
// NOTE (r16/r17): cooperative grids > 256 blocks silently fail. Grid == 256.
// ---------------------------------------------------------------------------
__global__ __launch_bounds__(1024) void gru_persist(
    const unsigned short* __restrict__ whh_hi,
    const unsigned short* __restrict__ whh_lo,
    const float* __restrict__ W_ihT,
    const float* __restrict__ b_ih,
    const float* __restrict__ b_hh,
    const float* __restrict__ h0,
    const int* __restrict__ ids,
    unsigned short* ghi,                 // (SEQ+1) slices of 64x1024
    unsigned short* glo,
    float* hn_out,                       // d_out tail (64x1024)
    int* flag,                           // 256 flags, stride 32 ints
    const unsigned short* __restrict__ wout_hi,   // 4000 x 1024
    const unsigned short* __restrict__ wout_lo,
    const float* __restrict__ b_out,
    float* __restrict__ C)               // 16384 x 4000 logits
{
    __shared__ f32x4 red[2][16][3][65];  // parity dbuf + pad, ~99.8 KB
    __shared__ int epi_cnt;              // monotone, 4 per step

    const int tid = threadIdx.x;
    const int w   = tid >> 6;            // 0..15 (K-split)
    const int l   = tid & 63;
    const int bid = blockIdx.x;
    const int grp   = bid & 7;           // XCD (round-robin dispatch)
    const int local = bid >> 3;          // 0..31
    const int jt  = grp * 8 + (local >> 2);
    const int mt  = local & 3;
    const int j0  = jt * 16;
    const int m0  = mt * 16;
    const int col = l & 15, kg = l >> 4;

    const size_t arow   = (size_t)(m0 + col) * HID;
    const size_t brow_r = (size_t)(j0 + col) * HID;
    const size_t brow_z = (size_t)(HID + j0 + col) * HID;
    const size_t brow_n = (size_t)(2 * HID + j0 + col) * HID;
    const int kbase = w * 64 + kg * 8;

    // ---- hoist this wave's weight fragments into registers (48 VGPRs) ----
    short8 wr_h[2], wr_l[2], wz_h[2], wz_l[2], wn_h[2], wn_l[2];
    #pragma unroll
    for (int c = 0; c < 2; ++c) {
        const int ko = kbase + c * 32;
        wr_h[c] = *(const short8*)(whh_hi + brow_r + ko);
        wr_l[c] = *(const short8*)(whh_lo + brow_r + ko);
        wz_h[c] = *(const short8*)(whh_hi + brow_z + ko);
        wz_l[c] = *(const short8*)(whh_lo + brow_z + ko);
        wn_h[c] = *(const short8*)(whh_hi + brow_n + ko);
        wn_l[c] = *(const short8*)(whh_lo + brow_n + ko);
    }

    // epilogue persistent state: tid<256, 1 thread = 1 output (b, j)
    const int bi = (tid >> 4) & 15;
    const int cj = tid & 15;
    const int eb = m0 + bi, ej = j0 + cj;
    float hreg = 0.f, xr_n = 0.f, xz_n = 0.f, xn_n = 0.f;
    float bihr = 0.f, bihz = 0.f, bihn = 0.f;
    float bhhr = 0.f, bhhz = 0.f, bhhn = 0.f;
    if (tid < 256) {
        hreg = h0[(size_t)eb * HID + ej];
        bihr = b_ih[ej]; bihz = b_ih[HID + ej]; bihn = b_ih[2 * HID + ej];
        bhhr = b_hh[ej]; bhhz = b_hh[HID + ej]; bhhn = b_hh[2 * HID + ej];
        const int id0 = ids[eb * SEQ];
        const float* xrow = W_ihT + (size_t)id0 * H3;
        xr_n = xrow[ej]; xz_n = xrow[HID + ej]; xn_n = xrow[2 * HID + ej];
    }
    const int lane = ((bi & 15) >> 2) * 16 + cj;   // MFMA C-layout inverse
    const int reg  = bi & 3;

    // fused-GEMM per-wave constants (waves 4-7; nt = w-4)
    const int gncol = jt * 64 + (w - 4) * 16 + col;        // n for this lane
    const bool gnok = (w >= 4 && w < 8) && (gncol < VOCAB);
    const size_t gwrow = gnok ? (size_t)gncol * HID : 0;
    const float gbias  = gnok ? b_out[gncol] : 0.f;
    const short8 zz = {0, 0, 0, 0, 0, 0, 0, 0};

// GEMM of history slice S (valid after barrier orders its polls).
// C rows = (S-1)*64 + mt*16 + kg*4 + r ; cols = gncol. Bitwise-identical
// accumulation order to the old standalone out_gemm.
#define FUSED_GEMM(S)                                                         \
    {                                                                         \
        const unsigned short* Ah_ = ghi + (size_t)(S) * HSLICE + arow;        \
        const unsigned short* Al_ = glo + (size_t)(S) * HSLICE + arow;        \
        f32x4 gacc = {0.f, 0.f, 0.f, 0.f};                                    \
        _Pragma("unroll 2")                                                   \
        for (int c = 0; c < 32; ++c) {                                        \
            const int ko = c * 32 + kg * 8;                                   \
            short8 a_h = *(const short8*)(Ah_ + ko);                          \
            short8 a_l = *(const short8*)(Al_ + ko);                          \
            short8 w_h = gnok ? *(const short8*)(wout_hi + gwrow + ko) : zz;  \
            short8 w_l = gnok ? *(const short8*)(wout_lo + gwrow + ko) : zz;  \
            gacc = __builtin_amdgcn_mfma_f32_16x16x32_bf16(a_h, w_h, gacc, 0, 0, 0); \
            gacc = __builtin_amdgcn_mfma_f32_16x16x32_bf16(a_h, w_l, gacc, 0, 0, 0); \
            gacc = __builtin_amdgcn_mfma_f32_16x16x32_bf16(a_l, w_h, gacc, 0, 0, 0); \
        }                                                                     \
        if (gnok) {                                                           \
            _Pragma("unroll")                                                 \
            for (int r = 0; r < 4; ++r) {                                     \
                const int m = ((S) - 1) * 64 + m0 + kg * 4 + r;               \
                C[(size_t)m * VOCAB + gncol] = gacc[r] + gbias;               \
            }                                                                 \
        }                                                                     \
    }

    const int myflag = (jt * 4 + mt) * 32;          // this block's flag index
    const int pollfl = ((4 * w + (l & 3)) * 4 + mt) * 32;  // lanes 0-3 poll

    if (tid == 0) epi_cnt = 0;
    __syncthreads();

    for (int t = 0; t < SEQ; ++t) {
        // ---- dataflow wait: this wave's 4 producer tiles of slice t ----
        if (t > 0) {
            if (l < 4) {
                while (__hip_atomic_load(&flag[pollfl], __ATOMIC_RELAXED,
                                         __HIP_MEMORY_SCOPE_AGENT) < t)
                    __builtin_amdgcn_s_sleep(1);
            }
            asm volatile("" ::: "memory");   // no load hoisting above polls
        }

        const unsigned short* ah = ghi + (size_t)t * HSLICE;   // h_{t-1}
        const unsigned short* al = glo + (size_t)t * HSLICE;

        f32x4 accr = {0.f, 0.f, 0.f, 0.f};
        f32x4 accz = {0.f, 0.f, 0.f, 0.f};
        f32x4 accn = {0.f, 0.f, 0.f, 0.f};

        #pragma unroll
        for (int c = 0; c < 2; ++c) {
            const int ko = kbase + c * 32;
            short8 a_h = *(const short8*)(ah + arow + ko);
            short8 a_l = *(const short8*)(al + arow + ko);

            accr = __builtin_amdgcn_mfma_f32_16x16x32_bf16(a_h, wr_h[c], accr, 0, 0, 0);
            accr = __builtin_amdgcn_mfma_f32_16x16x32_bf16(a_h, wr_l[c], accr, 0, 0, 0);
            accr = __builtin_amdgcn_mfma_f32_16x16x32_bf16(a_l, wr_h[c], accr, 0, 0, 0);

            accz = __builtin_amdgcn_mfma_f32_16x16x32_bf16(a_h, wz_h[c], accz, 0, 0, 0);
            accz = __builtin_amdgcn_mfma_f32_16x16x32_bf16(a_h, wz_l[c], accz, 0, 0, 0);
            accz = __builtin_amdgcn_mfma_f32_16x16x32_bf16(a_l, wz_h[c], accz, 0, 0, 0);

            accn = __builtin_amdgcn_mfma_f32_16x16x32_bf16(a_h, wn_h[c], accn, 0, 0, 0);
            accn = __builtin_amdgcn_mfma_f32_16x16x32_bf16(a_h, wn_l[c], accn, 0, 0, 0);
            accn = __builtin_amdgcn_mfma_f32_16x16x32_bf16(a_l, wn_h[c], accn, 0, 0, 0);
        }

        const int par = t & 1;
        red[par][w][0][l] = accr;
        red[par][w][1][l] = accz;
        red[par][w][2][l] = accn;
        __syncthreads();                 // barrier #1 (the only one)

        if (tid < 256) {
            float sr = 0.f, sz = 0.f, sn = 0.f;
            #pragma unroll
            for (int kk = 0; kk < 16; ++kk) {
                sr += ((const float*)&red[par][kk][0][lane])[reg];
                sz += ((const float*)&red[par][kk][1][lane])[reg];
                sn += ((const float*)&red[par][kk][2][lane])[reg];
            }
            const float xr = xr_n + bihr;
            const float xz = xz_n + bihz;
            const float xn = xn_n + bihn;
            const float rg = 1.f / (1.f + expf(-(xr + sr + bhhr)));
            const float zg = 1.f / (1.f + expf(-(xz + sz + bhhz)));
            const float ng = tanhf(xn + rg * (sn + bhhn));
            hreg = (1.f - zg) * ng + zg * hreg;

            // ---- h store: packed u32, agent-scope write-through (sc1) ----
            const unsigned short hh = f2bf(hreg);
            const unsigned short ll = f2bf(hreg - bf2f(hh));
            const unsigned int hh_n = (unsigned int)(unsigned short)
                __shfl_xor((int)hh, 1, 64);
            const unsigned int ll_n = (unsigned int)(unsigned short)
                __shfl_xor((int)ll, 1, 64);
            const size_t ho = (size_t)(t + 1) * HSLICE + (size_t)eb * HID + ej;
            if ((cj & 1) == 0) {
                const unsigned int hp = (unsigned int)hh | (hh_n << 16);
                const unsigned int lp = (unsigned int)ll | (ll_n << 16);
                __hip_atomic_store((unsigned int*)ghi + (ho >> 1), hp,
                                   __ATOMIC_RELAXED, __HIP_MEMORY_SCOPE_AGENT);
                __hip_atomic_store((unsigned int*)glo + (ho >> 1), lp,
                                   __ATOMIC_RELAXED, __HIP_MEMORY_SCOPE_AGENT);
            }

            // per-wave drain -> LDS last-arriver publishes the block flag
            asm volatile("s_waitcnt vmcnt(0)" ::: "memory");
            if (l == 0) {
                const int old = atomicAdd(&epi_cnt, 1);
                if (old == 4 * t + 3) {
                    __hip_atomic_store(&flag[myflag], t + 1, __ATOMIC_RELAXED,
                                       __HIP_MEMORY_SCOPE_AGENT);
                }
            }

            // prefetch next x_proj row AFTER publish (outside drain set)
            if (t + 1 < SEQ) {
                const int id2 = ids[eb * SEQ + t + 1];
                const float* xrow = W_ihT + (size_t)id2 * H3;
                xr_n = xrow[ej]; xz_n = xrow[HID + ej]; xn_n = xrow[2 * HID + ej];
            } else {
                hn_out[(size_t)eb * HID + ej] = hreg;
            }
        } else if (w < 8) {
            // ---- fused output GEMM of slice t (gru_out row-block t-1),
            //      hidden under the producers' publish path ----
            if (t >= 1) FUSED_GEMM(t)
        }
        // no barrier #2: waves 4-15 proceed straight to polling t+1;
        // red[] reuse at t+2 is ordered through barrier#1(t+1).
    }

    // ---- tail: final history slice (SEQ) -> C rows (SEQ-1)*64.. ----
    if (l < 4) {
        while (__hip_atomic_load(&flag[pollfl], __ATOMIC_RELAXED,
                                 __HIP_MEMORY_SCOPE_AGENT) < SEQ)
            __builtin_amdgcn_s_sleep(1);
    }
    asm volatile("" ::: "memory");
    __syncthreads();                     // slice SEQ block-visible
    if (tid >= 256 && w < 8) {
        FUSED_GEMM(SEQ)
    }
#undef FUSED_GEMM
}

extern "C" void kernel_launch(void* const* d_in, const int* in_sizes, int n_in,
                              void* d_out, int out_size, void* d_ws, size_t ws_size,
                              hipStream_t stream) {
    const int*   inputs = (const int*)d_in[0];
    const float* h0     = (const float*)d_in[1];
    const float* W_ih   = (const float*)d_in[2];
    const float* W_hh   = (const float*)d_in[3];
    const float* b_ih   = (const float*)d_in[4];
    const float* b_hh   = (const float*)d_in[5];
    const float* W_out  = (const float*)d_in[6];
    const float* b_out  = (const float*)d_in[7];
    float* out = (float*)d_out;

    // workspace layout
    char* p = (char*)d_ws;
    unsigned short* ghi     = (unsigned short*)p; p += (size_t)(SEQ + 1) * HSLICE * 2;
    unsigned short* glo     = (unsigned short*)p; p += (size_t)(SEQ + 1) * HSLICE * 2;
    unsigned short* whh_hi  = (unsigned short*)p; p += (size_t)3 * HID * HID * 2;
    unsigned short* whh_lo  = (unsigned short*)p; p += (size_t)3 * HID * HID * 2;
    unsigned short* wout_hi = (unsigned short*)p; p += (size_t)VOCAB * HID * 2;
    unsigned short* wout_lo = (unsigned short*)p; p += (size_t)VOCAB * HID * 2;
    float* W_ihT            = (float*)p;          p += (size_t)VOCAB * H3 * 4;
    int* bar                = (int*)p;            p += 8192 * 4;

    split_kernel<<<2048, 256, 0, stream>>>(W_hh, W_out, h0,
        whh_hi, whh_lo, wout_hi, wout_lo, ghi /*slice 0*/, glo /*slice 0*/);
    transpose_wih<<<dim3(VOCAB / 32, H3 / 32), 256, 0, stream>>>(W_ih, W_ihT);
    zero_barrier<<<8, 1024, 0, stream>>>(bar);

    float* hn_out = out + (size_t)SEQ * BATCH * VOCAB;
    const unsigned short* a_whh_hi = whh_hi;
    const unsigned short* a_whh_lo = whh_lo;
    const float* a_wihT = W_ihT;
    const float* a_bih = b_ih;
    const float* a_bhh = b_hh;
    const float* a_h0 = h0;
    const int* a_ids = inputs;
    unsigned short* a_ghi = ghi;
    unsigned short* a_glo = glo;
    int* a_bar = bar;
    const unsigned short* a_wout_hi = wout_hi;
    const unsigned short* a_wout_lo = wout_lo;
    const float* a_bout = b_out;
    float* a_C = out;
    void* kargs[] = { (void*)&a_whh_hi, (void*)&a_whh_lo, (void*)&a_wihT,
                      (void*)&a_bih, (void*)&a_bhh, (void*)&a_h0, (void*)&a_ids,
                      (void*)&a_ghi, (void*)&a_glo, (void*)&hn_out, (void*)&a_bar,
                      (void*)&a_wout_hi, (void*)&a_wout_lo, (void*)&a_bout,
                      (void*)&a_C };
    hipLaunchCooperativeKernel((const void*)gru_persist, dim3(256), dim3(1024),
                               kargs, 0, stream);
}

// Round 20
// 1447.390 us; speedup vs baseline: 3.0209x; 3.0209x over previous
//
#include <hip/hip_runtime.h>
#include <math.h>

#define SEQ 256
#define BATCH 64
#define HID 1024
#define VOCAB 4000
#define H3 (3 * HID)
#define HSLICE (BATCH * HID)

typedef __attribute__((ext_vector_type(8))) short short8;
typedef __attribute__((ext_vector_type(4))) float f32x4;

__device__ inline unsigned short f2bf(float x) {
    unsigned int u = __builtin_bit_cast(unsigned int, x);
    unsigned int r = (u + 0x7fffu + ((u >> 16) & 1u)) >> 16;   // RNE
    return (unsigned short)r;
}
__device__ inline float bf2f(unsigned short h) {
    unsigned int u = ((unsigned int)h) << 16;
    return __builtin_bit_cast(float, u);
}

// ---------------------------------------------------------------------------
// Split f32 arrays into bf16 hi/lo pairs. h0 goes into slice 0 of the
// h-history (so the persistent kernel has no t==0 special case).
// ---------------------------------------------------------------------------
__global__ __launch_bounds__(256) void split_kernel(
    const float* __restrict__ W_hh, const float* __restrict__ W_out,
    const float* __restrict__ h0,
    unsigned short* __restrict__ whh_hi, unsigned short* __restrict__ whh_lo,
    unsigned short* __restrict__ wout_hi, unsigned short* __restrict__ wout_lo,
    unsigned short* __restrict__ h0_hi, unsigned short* __restrict__ h0_lo)
{
    const int NW = 3 * HID * HID;
    const int NO = VOCAB * HID;
    const int NH = BATCH * HID;
    const int total = NW + NO + NH;
    for (int i = blockIdx.x * blockDim.x + threadIdx.x; i < total;
         i += gridDim.x * blockDim.x) {
        const float* src; unsigned short *dh, *dl; int off;
        if (i < NW)           { src = W_hh;  dh = whh_hi;  dl = whh_lo;  off = i; }
        else if (i < NW + NO) { src = W_out; dh = wout_hi; dl = wout_lo; off = i - NW; }
        else                  { src = h0;    dh = h0_hi;   dl = h0_lo;   off = i - NW - NO; }
        float x = src[off];
        unsigned short hi = f2bf(x);
        dh[off] = hi;
        dl[off] = f2bf(x - bf2f(hi));
    }
}

// ---------------------------------------------------------------------------
// W_ih (3072 x 4000) -> W_ihT (4000 x 3072), 32x32 LDS tiles.
// ---------------------------------------------------------------------------
__global__ __launch_bounds__(256) void transpose_wih(
    const float* __restrict__ W_ih, float* __restrict__ W_ihT)
{
    __shared__ float tile[32][33];
    const int tx = threadIdx.x & 31;
    const int ty = threadIdx.x >> 5;          // 0..7
    const int r0 = blockIdx.y * 32;           // 3072-dim base
    const int c0 = blockIdx.x * 32;           // 4000-dim base
    #pragma unroll
    for (int k = 0; k < 4; ++k) {
        const int r = ty + k * 8;
        tile[r][tx] = W_ih[(size_t)(r0 + r) * VOCAB + c0 + tx];  // 4000%32==0
    }
    __syncthreads();
    #pragma unroll
    for (int k = 0; k < 4; ++k) {
        const int r = ty + k * 8;
        W_ihT[(size_t)(c0 + r) * H3 + r0 + tx] = tile[tx][r];
    }
}

__global__ void zero_barrier(int* b) {                    // 8192 ints (32 KB)
    b[blockIdx.x * 1024 + threadIdx.x] = 0;
}

// ---------------------------------------------------------------------------
// Persistent cooperative GRU: round-10 LLC protocol (one flag per block,
// 4-flag polls, agent-scope write-through h-stores, no fences) with the
// intra-block barrier #2 eliminated (round-15 refinement, best measured:
// gru ~1093 us, 4.27 us/step):
//   - red[] parity-double-buffered (pad 65): no trailing barrier for reuse.
//   - last-arriver publish: each epilogue wave drains its OWN vmcnt(0),
//     bumps an LDS counter; the 4th wave stores the block flag.
//   - waves 4-15 go straight from barrier#1 to polling/loading t+1.
// NOTES: coop grids > 256 blocks silently fail (r16/r17). Fusing the output
// GEMM into the poll slack regresses 3x (r19): a latency-bound loop cannot
// absorb another latency-bound loop on its critical path.
// ---------------------------------------------------------------------------
__global__ __launch_bounds__(1024) void gru_persist(
    const unsigned short* __restrict__ whh_hi,
    const unsigned short* __restrict__ whh_lo,
    const float* __restrict__ W_ihT,
    const float* __restrict__ b_ih,
    const float* __restrict__ b_hh,
    const float* __restrict__ h0,
    const int* __restrict__ ids,
    unsigned short* ghi,                 // (SEQ+1) slices of 64x1024
    unsigned short* glo,
    float* hn_out,                       // d_out tail (64x1024)
    int* flag)                           // 256 flags, stride 32 ints
{
    __shared__ f32x4 red[2][16][3][65];  // parity dbuf + pad, ~99.8 KB
    __shared__ int epi_cnt;              // monotone, 4 per step

    const int tid = threadIdx.x;
    const int w   = tid >> 6;            // 0..15 (K-split)
    const int l   = tid & 63;
    const int bid = blockIdx.x;
    const int grp   = bid & 7;           // XCD (round-robin dispatch)
    const int local = bid >> 3;          // 0..31
    const int jt  = grp * 8 + (local >> 2);
    const int mt  = local & 3;
    const int j0  = jt * 16;
    const int m0  = mt * 16;
    const int col = l & 15, kg = l >> 4;

    const size_t arow   = (size_t)(m0 + col) * HID;
    const size_t brow_r = (size_t)(j0 + col) * HID;
    const size_t brow_z = (size_t)(HID + j0 + col) * HID;
    const size_t brow_n = (size_t)(2 * HID + j0 + col) * HID;
    const int kbase = w * 64 + kg * 8;

    // ---- hoist this wave's weight fragments into registers (48 VGPRs) ----
    short8 wr_h[2], wr_l[2], wz_h[2], wz_l[2], wn_h[2], wn_l[2];
    #pragma unroll
    for (int c = 0; c < 2; ++c) {
        const int ko = kbase + c * 32;
        wr_h[c] = *(const short8*)(whh_hi + brow_r + ko);
        wr_l[c] = *(const short8*)(whh_lo + brow_r + ko);
        wz_h[c] = *(const short8*)(whh_hi + brow_z + ko);
        wz_l[c] = *(const short8*)(whh_lo + brow_z + ko);
        wn_h[c] = *(const short8*)(whh_hi + brow_n + ko);
        wn_l[c] = *(const short8*)(whh_lo + brow_n + ko);
    }

    // epilogue persistent state: tid<256, 1 thread = 1 output (b, j)
    const int bi = (tid >> 4) & 15;
    const int cj = tid & 15;
    const int eb = m0 + bi, ej = j0 + cj;
    float hreg = 0.f, xr_n = 0.f, xz_n = 0.f, xn_n = 0.f;
    float bihr = 0.f, bihz = 0.f, bihn = 0.f;
    float bhhr = 0.f, bhhz = 0.f, bhhn = 0.f;
    if (tid < 256) {
        hreg = h0[(size_t)eb * HID + ej];
        bihr = b_ih[ej]; bihz = b_ih[HID + ej]; bihn = b_ih[2 * HID + ej];
        bhhr = b_hh[ej]; bhhz = b_hh[HID + ej]; bhhn = b_hh[2 * HID + ej];
        const int id0 = ids[eb * SEQ];
        const float* xrow = W_ihT + (size_t)id0 * H3;
        xr_n = xrow[ej]; xz_n = xrow[HID + ej]; xn_n = xrow[2 * HID + ej];
    }
    const int lane = ((bi & 15) >> 2) * 16 + cj;   // MFMA C-layout inverse
    const int reg  = bi & 3;

    const int myflag = (jt * 4 + mt) * 32;          // this block's flag index
    const int pollfl = ((4 * w + (l & 3)) * 4 + mt) * 32;  // lanes 0-3 poll

    if (tid == 0) epi_cnt = 0;
    __syncthreads();

    for (int t = 0; t < SEQ; ++t) {
        // ---- dataflow wait: this wave's 4 producer tiles of slice t ----
        if (t > 0) {
            if (l < 4) {
                while (__hip_atomic_load(&flag[pollfl], __ATOMIC_RELAXED,
                                         __HIP_MEMORY_SCOPE_AGENT) < t)
                    __builtin_amdgcn_s_sleep(1);
            }
            asm volatile("" ::: "memory");   // no load hoisting above polls
        }

        const unsigned short* ah = ghi + (size_t)t * HSLICE;   // h_{t-1}
        const unsigned short* al = glo + (size_t)t * HSLICE;

        f32x4 accr = {0.f, 0.f, 0.f, 0.f};
        f32x4 accz = {0.f, 0.f, 0.f, 0.f};
        f32x4 accn = {0.f, 0.f, 0.f, 0.f};

        #pragma unroll
        for (int c = 0; c < 2; ++c) {
            const int ko = kbase + c * 32;
            short8 a_h = *(const short8*)(ah + arow + ko);
            short8 a_l = *(const short8*)(al + arow + ko);

            accr = __builtin_amdgcn_mfma_f32_16x16x32_bf16(a_h, wr_h[c], accr, 0, 0, 0);
            accr = __builtin_amdgcn_mfma_f32_16x16x32_bf16(a_h, wr_l[c], accr, 0, 0, 0);
            accr = __builtin_amdgcn_mfma_f32_16x16x32_bf16(a_l, wr_h[c], accr, 0, 0, 0);

            accz = __builtin_amdgcn_mfma_f32_16x16x32_bf16(a_h, wz_h[c], accz, 0, 0, 0);
            accz = __builtin_amdgcn_mfma_f32_16x16x32_bf16(a_h, wz_l[c], accz, 0, 0, 0);
            accz = __builtin_amdgcn_mfma_f32_16x16x32_bf16(a_l, wz_h[c], accz, 0, 0, 0);

            accn = __builtin_amdgcn_mfma_f32_16x16x32_bf16(a_h, wn_h[c], accn, 0, 0, 0);
            accn = __builtin_amdgcn_mfma_f32_16x16x32_bf16(a_h, wn_l[c], accn, 0, 0, 0);
            accn = __builtin_amdgcn_mfma_f32_16x16x32_bf16(a_l, wn_h[c], accn, 0, 0, 0);
        }

        const int par = t & 1;
        red[par][w][0][l] = accr;
        red[par][w][1][l] = accz;
        red[par][w][2][l] = accn;
        __syncthreads();                 // barrier #1 (the only one)

        if (tid < 256) {
            float sr = 0.f, sz = 0.f, sn = 0.f;
            #pragma unroll
            for (int kk = 0; kk < 16; ++kk) {
                sr += ((const float*)&red[par][kk][0][lane])[reg];
                sz += ((const float*)&red[par][kk][1][lane])[reg];
                sn += ((const float*)&red[par][kk][2][lane])[reg];
            }
            const float xr = xr_n + bihr;
            const float xz = xz_n + bihz;
            const float xn = xn_n + bihn;
            const float rg = 1.f / (1.f + expf(-(xr + sr + bhhr)));
            const float zg = 1.f / (1.f + expf(-(xz + sz + bhhz)));
            const float ng = tanhf(xn + rg * (sn + bhhn));
            hreg = (1.f - zg) * ng + zg * hreg;

            // ---- h store: packed u32, agent-scope write-through (sc1) ----
            const unsigned short hh = f2bf(hreg);
            const unsigned short ll = f2bf(hreg - bf2f(hh));
            const unsigned int hh_n = (unsigned int)(unsigned short)
                __shfl_xor((int)hh, 1, 64);
            const unsigned int ll_n = (unsigned int)(unsigned short)
                __shfl_xor((int)ll, 1, 64);
            const size_t ho = (size_t)(t + 1) * HSLICE + (size_t)eb * HID + ej;
            if ((cj & 1) == 0) {
                const unsigned int hp = (unsigned int)hh | (hh_n << 16);
                const unsigned int lp = (unsigned int)ll | (ll_n << 16);
                __hip_atomic_store((unsigned int*)ghi + (ho >> 1), hp,
                                   __ATOMIC_RELAXED, __HIP_MEMORY_SCOPE_AGENT);
                __hip_atomic_store((unsigned int*)glo + (ho >> 1), lp,
                                   __ATOMIC_RELAXED, __HIP_MEMORY_SCOPE_AGENT);
            }

            // per-wave drain -> LDS last-arriver publishes the block flag
            asm volatile("s_waitcnt vmcnt(0)" ::: "memory");
            if (l == 0) {
                const int old = atomicAdd(&epi_cnt, 1);
                if (old == 4 * t + 3) {
                    __hip_atomic_store(&flag[myflag], t + 1, __ATOMIC_RELAXED,
                                       __HIP_MEMORY_SCOPE_AGENT);
                }
            }

            // prefetch next x_proj row AFTER publish (outside drain set)
            if (t + 1 < SEQ) {
                const int id2 = ids[eb * SEQ + t + 1];
                const float* xrow = W_ihT + (size_t)id2 * H3;
                xr_n = xrow[ej]; xz_n = xrow[HID + ej]; xn_n = xrow[2 * HID + ej];
            } else {
                hn_out[(size_t)eb * HID + ej] = hreg;
            }
        }
        // no barrier #2: waves 4-15 proceed straight to polling t+1;
        // red[] reuse at t+2 is ordered through barrier#1(t+1).
    }
}

// ---------------------------------------------------------------------------
// Output GEMM, split-bf16 MFMA — round-14 version (frozen):
// xb-major per-XCD order + 2-phase reg-staged double-buffer.
// ---------------------------------------------------------------------------
__global__ __launch_bounds__(256) void out_gemm_mfma(
    const unsigned short* __restrict__ Ahi_g,  // 16384 x 1024
    const unsigned short* __restrict__ Alo_g,
    const unsigned short* __restrict__ Bhi_g,  // 4000 x 1024
    const unsigned short* __restrict__ Blo_g,
    const float* __restrict__ bias,
    float* __restrict__ C)
{
    constexpr int BM = 128, BK = 32, LDK = 40;
    __shared__ unsigned short Ah[2][BM * LDK], Al[2][BM * LDK];
    __shared__ unsigned short Bh[2][BM * LDK], Bl[2][BM * LDK];   // 80 KB

    const int tid = threadIdx.x;
    const int l = tid & 63, w = tid >> 6;
    const int wr = w >> 1, wc = w & 1;
    const int col = l & 15, kg = l >> 4;
    const int bid = blockIdx.x;
    const int xcd = bid & 7;
    const int q   = bid >> 3;                 // 0..511
    const int xb  = q >> 2;                   // 0..127 (m-tile, xb-major)
    const int yb  = xcd * 4 + (q & 3);        // 0..31  (n-tile)
    const int m0 = xb * BM;
    const int n0 = yb * BM;

    const int row0 = tid >> 2,        kq0 = tid & 3;
    const int row1 = (tid + 256) >> 2, kq1 = (tid + 256) & 3;

    f32x4 acc[4][4];
    #pragma unroll
    for (int i = 0; i < 4; ++i)
        #pragma unroll
        for (int jt = 0; jt < 4; ++jt)
            acc[i][jt] = (f32x4){0.f, 0.f, 0.f, 0.f};

    short8 pAh[2], pAl[2], pBh[2], pBl[2];
#define PREFETCH(KC)                                                          \
    {                                                                         \
        _Pragma("unroll")                                                     \
        for (int i = 0; i < 2; ++i) {                                         \
            const int row = i ? row1 : row0;                                  \
            const int kq  = i ? kq1  : kq0;                                   \
            const int go  = (KC) + kq * 8;                                    \
            pAh[i] = *(const short8*)(Ahi_g + (size_t)(m0 + row) * HID + go); \
            pAl[i] = *(const short8*)(Alo_g + (size_t)(m0 + row) * HID + go); \
            const int n = n0 + row;                                           \
            short8 vh = {0,0,0,0,0,0,0,0}, vl = {0,0,0,0,0,0,0,0};            \
            if (n < VOCAB) {                                                  \
                vh = *(const short8*)(Bhi_g + (size_t)n * HID + go);          \
                vl = *(const short8*)(Blo_g + (size_t)n * HID + go);          \
            }                                                                 \
            pBh[i] = vh; pBl[i] = vl;                                         \
        }                                                                     \
    }
#define WRITE_LDS(BUF)                                                        \
    {                                                                         \
        _Pragma("unroll")                                                     \
        for (int i = 0; i < 2; ++i) {                                         \
            const int row = i ? row1 : row0;                                  \
            const int kq  = i ? kq1  : kq0;                                   \
            *(short8*)(&Ah[BUF][row * LDK + kq * 8]) = pAh[i];                \
            *(short8*)(&Al[BUF][row * LDK + kq * 8]) = pAl[i];                \
            *(short8*)(&Bh[BUF][row * LDK + kq * 8]) = pBh[i];                \
            *(short8*)(&Bl[BUF][row * LDK + kq * 8]) = pBl[i];                \
        }                                                                     \
    }

    PREFETCH(0)
    WRITE_LDS(0)
    int cur = 0;

    for (int c = 0; c < HID / BK; ++c) {
        __syncthreads();
        if (c + 1 < HID / BK) PREFETCH((c + 1) * BK)

        short8 af_h[4], af_l[4], bf_h[4], bf_l[4];
        #pragma unroll
        for (int i = 0; i < 4; ++i) {
            const int r = wr * 64 + i * 16 + col;
            af_h[i] = *(const short8*)(&Ah[cur][r * LDK + kg * 8]);
            af_l[i] = *(const short8*)(&Al[cur][r * LDK + kg * 8]);
        }
        #pragma unroll
        for (int jt = 0; jt < 4; ++jt) {
            const int r = wc * 64 + jt * 16 + col;
            bf_h[jt] = *(const short8*)(&Bh[cur][r * LDK + kg * 8]);
            bf_l[jt] = *(const short8*)(&Bl[cur][r * LDK + kg * 8]);
        }
        #pragma unroll
        for (int i = 0; i < 4; ++i)
            #pragma unroll
            for (int jt = 0; jt < 4; ++jt) {
                acc[i][jt] = __builtin_amdgcn_mfma_f32_16x16x32_bf16(af_h[i], bf_h[jt], acc[i][jt], 0, 0, 0);
                acc[i][jt] = __builtin_amdgcn_mfma_f32_16x16x32_bf16(af_h[i], bf_l[jt], acc[i][jt], 0, 0, 0);
                acc[i][jt] = __builtin_amdgcn_mfma_f32_16x16x32_bf16(af_l[i], bf_h[jt], acc[i][jt], 0, 0, 0);
            }
        if (c + 1 < HID / BK) WRITE_LDS(cur ^ 1)
        cur ^= 1;
    }
#undef PREFETCH
#undef WRITE_LDS

    #pragma unroll
    for (int i = 0; i < 4; ++i)
        #pragma unroll
        for (int jt = 0; jt < 4; ++jt)
            #pragma unroll
            for (int r = 0; r < 4; ++r) {
                const int m = m0 + wr * 64 + i * 16 + kg * 4 + r;
                const int n = n0 + wc * 64 + jt * 16 + col;
                if (n < VOCAB)
                    C[(size_t)m * VOCAB + n] = acc[i][jt][r] + bias[n];
            }
}

extern "C" void kernel_launch(void* const* d_in, const int* in_sizes, int n_in,
                              void* d_out, int out_size, void* d_ws, size_t ws_size,
                              hipStream_t stream) {
    const int*   inputs = (const int*)d_in[0];
    const float* h0     = (const float*)d_in[1];
    const float* W_ih   = (const float*)d_in[2];
    const float* W_hh   = (const float*)d_in[3];
    const float* b_ih   = (const float*)d_in[4];
    const float* b_hh   = (const float*)d_in[5];
    const float* W_out  = (const float*)d_in[6];
    const float* b_out  = (const float*)d_in[7];
    float* out = (float*)d_out;

    // workspace layout
    char* p = (char*)d_ws;
    unsigned short* ghi     = (unsigned short*)p; p += (size_t)(SEQ + 1) * HSLICE * 2;
    unsigned short* glo     = (unsigned short*)p; p += (size_t)(SEQ + 1) * HSLICE * 2;
    unsigned short* whh_hi  = (unsigned short*)p; p += (size_t)3 * HID * HID * 2;
    unsigned short* whh_lo  = (unsigned short*)p; p += (size_t)3 * HID * HID * 2;
    unsigned short* wout_hi = (unsigned short*)p; p += (size_t)VOCAB * HID * 2;
    unsigned short* wout_lo = (unsigned short*)p; p += (size_t)VOCAB * HID * 2;
    float* W_ihT            = (float*)p;          p += (size_t)VOCAB * H3 * 4;
    int* bar                = (int*)p;            p += 8192 * 4;

    split_kernel<<<2048, 256, 0, stream>>>(W_hh, W_out, h0,
        whh_hi, whh_lo, wout_hi, wout_lo, ghi /*slice 0*/, glo /*slice 0*/);
    transpose_wih<<<dim3(VOCAB / 32, H3 / 32), 256, 0, stream>>>(W_ih, W_ihT);
    zero_barrier<<<8, 1024, 0, stream>>>(bar);

    float* hn_out = out + (size_t)SEQ * BATCH * VOCAB;
    const unsigned short* a_whh_hi = whh_hi;
    const unsigned short* a_whh_lo = whh_lo;
    const float* a_wihT = W_ihT;
    const float* a_bih = b_ih;
    const float* a_bhh = b_hh;
    const float* a_h0 = h0;
    const int* a_ids = inputs;
    unsigned short* a_ghi = ghi;
    unsigned short* a_glo = glo;
    int* a_bar = bar;
    void* kargs[] = { (void*)&a_whh_hi, (void*)&a_whh_lo, (void*)&a_wihT,
                      (void*)&a_bih, (void*)&a_bhh, (void*)&a_h0, (void*)&a_ids,
                      (void*)&a_ghi, (void*)&a_glo, (void*)&hn_out, (void*)&a_bar };
    hipLaunchCooperativeKernel((const void*)gru_persist, dim3(256), dim3(1024),
                               kargs, 0, stream);

    out_gemm_mfma<<<4096, 256, 0, stream>>>(
        ghi + HSLICE, glo + HSLICE, wout_hi, wout_lo, b_out, out);
}